// Round 1
// baseline (195.457 us; speedup 1.0000x reference)
//
#include <hip/hip_runtime.h>

#define BATCH 2
#define SEQ 2048
#define DMODEL 768
#define NH 12
#define DHEAD 64
#define D3 (3 * DMODEL)  // 2304

typedef float f32x4 __attribute__((ext_vector_type(4)));
typedef __bf16 bf16x8 __attribute__((ext_vector_type(8)));
typedef __bf16 bf16x4 __attribute__((ext_vector_type(4)));

__device__ __forceinline__ void g2l16(const void* g, void* l) {
    __builtin_amdgcn_global_load_lds(
        (const __attribute__((address_space(1))) void*)g,
        (__attribute__((address_space(3))) void*)l,
        16, 0, 0);
}

// ---------------- f32 -> bf16 convert (4 elems/thread) ----------------
__global__ __launch_bounds__(256) void cvt_bf16_kernel(const float* __restrict__ in,
                                                       __bf16* __restrict__ out, int n4) {
    int i = blockIdx.x * 256 + threadIdx.x;
    if (i >= n4) return;
    float4 v = ((const float4*)in)[i];
    bf16x4 o;
    o[0] = (__bf16)v.x; o[1] = (__bf16)v.y; o[2] = (__bf16)v.z; o[3] = (__bf16)v.w;
    ((bf16x4*)out)[i] = o;
}

// ---------------- padding mask -> lengths, with dtype sniff ----------------
// If mask is int32 (harness "integer->int*" contract), bytes [0,4096) are all
// zero (lengths >= S/2 => first 1024 elems of row 0 are false). If bool (1B),
// those bytes contain the tails of rows 0 and 1 (nonzero unless no padding).
__global__ __launch_bounds__(256) void lens_kernel(const unsigned char* __restrict__ mask,
                                                   int* __restrict__ lens) {
    __shared__ int nz_s;
    __shared__ int cnt[2];
    if (threadIdx.x == 0) { nz_s = 0; cnt[0] = 0; cnt[1] = 0; }
    __syncthreads();
    uint4 mv = ((const uint4*)mask)[threadIdx.x];  // covers bytes [0,4096)
    if (mv.x | mv.y | mv.z | mv.w) nz_s = 1;
    __syncthreads();
    int c0 = 0, c1 = 0;
    if (nz_s) {  // bool layout, 1 byte/elem
        for (int s = threadIdx.x; s < SEQ; s += 256) {
            c0 += (mask[s] != 0);
            c1 += (mask[SEQ + s] != 0);
        }
    } else {     // int32 layout (also handles f32: nonzero bits == masked)
        const int* mi = (const int*)mask;
        for (int s = threadIdx.x; s < SEQ; s += 256) {
            c0 += (mi[s] != 0);
            c1 += (mi[SEQ + s] != 0);
        }
    }
    atomicAdd(&cnt[0], c0);
    atomicAdd(&cnt[1], c1);
    __syncthreads();
    if (threadIdx.x == 0) { lens[0] = SEQ - cnt[0]; lens[1] = SEQ - cnt[1]; }
}

// ---------------- NT GEMM: C[M,N] = A[M,K] * Bw[N,K]^T + bias ----------------
// 128x128 tile, BK=64, 4 waves, global_load_lds staging, 16x16x32 bf16 MFMA.
template <int OUT_F32>
__global__ __launch_bounds__(256) void gemm_bt(const __bf16* __restrict__ A,
                                               const __bf16* __restrict__ Bw,
                                               const float* __restrict__ bias,
                                               void* __restrict__ Cout,
                                               int M, int N, int K) {
    __shared__ __align__(16) __bf16 As[128][64];
    __shared__ __align__(16) __bf16 Bs[128][64];
    const int tid = threadIdx.x;
    const int wave = tid >> 6, lane = tid & 63;
    const int bm = blockIdx.x * 128, bn = blockIdx.y * 128;
    const int wr = (wave >> 1) * 64, wc = (wave & 1) * 64;
    const int l15 = lane & 15, lg = lane >> 4;
    const int rsub = lane >> 3;         // 0..7
    const int csub = (lane & 7) * 8;    // 0..56

    f32x4 acc[4][4] = {};

    for (int kt = 0; kt < K; kt += 64) {
#pragma unroll
        for (int it = 0; it < 4; ++it) {
            int c = it * 4 + wave;      // chunk 0..15, 1KB each
            int row = c * 8 + rsub;
            g2l16(A + (size_t)(bm + row) * K + kt + csub, &As[0][0] + c * 512);
            g2l16(Bw + (size_t)(bn + row) * K + kt + csub, &Bs[0][0] + c * 512);
        }
        __syncthreads();
#pragma unroll
        for (int kk = 0; kk < 2; ++kk) {
            bf16x8 af[4], bfr[4];
#pragma unroll
            for (int m = 0; m < 4; ++m)
                af[m] = *(const bf16x8*)&As[wr + m * 16 + l15][kk * 32 + lg * 8];
#pragma unroll
            for (int n = 0; n < 4; ++n)
                bfr[n] = *(const bf16x8*)&Bs[wc + n * 16 + l15][kk * 32 + lg * 8];
#pragma unroll
            for (int m = 0; m < 4; ++m)
#pragma unroll
                for (int n = 0; n < 4; ++n)
                    acc[m][n] = __builtin_amdgcn_mfma_f32_16x16x32_bf16(af[m], bfr[n], acc[m][n], 0, 0, 0);
        }
        __syncthreads();
    }

#pragma unroll
    for (int n = 0; n < 4; ++n) {
        int col = bn + wc + n * 16 + l15;
        float bv = bias[col];
#pragma unroll
        for (int m = 0; m < 4; ++m) {
#pragma unroll
            for (int j = 0; j < 4; ++j) {
                int row = bm + wr + m * 16 + lg * 4 + j;
                float v = acc[m][n][j] + bv;
                if (OUT_F32)
                    ((float*)Cout)[(size_t)row * N + col] = v;
                else
                    ((__bf16*)Cout)[(size_t)row * N + col] = (__bf16)v;
            }
        }
    }
}

// ---------------- flash attention: 1 block = 64 q-rows of one (b,h) ----------------
__global__ __launch_bounds__(256) void attn_kernel(const __bf16* __restrict__ QKV,
                                                   const int* __restrict__ lens,
                                                   __bf16* __restrict__ Out) {
    __shared__ __align__(16) __bf16 Ks[64][64];     // K tile, row-major [key][dh]
    __shared__ __align__(16) __bf16 Vs[64][72];     // V tile staged [key][dh], padded
    __shared__ __align__(16) __bf16 Vt[64][72];     // V^T [dh][key], padded
    __shared__ __align__(16) __bf16 Ps[4][16][72];  // per-wave P [q][key], padded

    const int tid = threadIdx.x;
    const int wave = tid >> 6, lane = tid & 63;
    const int l15 = lane & 15, lg = lane >> 4;
    const int qb = blockIdx.x * 64;
    const int b = blockIdx.y / NH, h = blockIdx.y % NH;
    const int len = lens[b];
    const __bf16* base = QKV + (size_t)b * SEQ * D3;

    // Q fragments (A-operand): row = lane&15, k = (lane>>4)*8 (+32 per kk)
    bf16x8 qf[2];
    {
        const __bf16* qp = base + (size_t)(qb + wave * 16 + l15) * D3 + h * DHEAD + lg * 8;
        qf[0] = *(const bf16x8*)qp;
        qf[1] = *(const bf16x8*)(qp + 32);
    }

    f32x4 accO[4] = {};
    float m_run[4], l_run[4];
#pragma unroll
    for (int j = 0; j < 4; ++j) { m_run[j] = -__builtin_inff(); l_run[j] = 0.f; }

    int kmax = qb + 64;
    if (len < kmax) kmax = len;
    const int ntiles = (kmax + 63) >> 6;

    for (int kt = 0; kt < ntiles; ++kt) {
        const int k0 = kt * 64;
        // ---- stage K (async direct-to-LDS) and V (regs -> padded LDS) ----
#pragma unroll
        for (int it = 0; it < 2; ++it) {
            int c = it * 4 + wave;
            int r = c * 8 + (lane >> 3);
            g2l16(base + (size_t)(k0 + r) * D3 + DMODEL + h * DHEAD + (lane & 7) * 8,
                  &Ks[0][0] + c * 512);
        }
#pragma unroll
        for (int it = 0; it < 2; ++it) {
            int idx = it * 256 + tid;
            int r = idx >> 3, c0 = (idx & 7) * 8;
            bf16x8 v = *(const bf16x8*)(base + (size_t)(k0 + r) * D3 + 2 * DMODEL + h * DHEAD + c0);
            *(bf16x8*)&Vs[r][c0] = v;
        }
        __syncthreads();

        // ---- transpose Vs -> Vt, one rotating wave, 8x8 blocks, b128 both ways ----
        if (wave == (kt & 3)) {
            int bi = lane >> 3, bj = lane & 7;
            bf16x8 rowv[8];
#pragma unroll
            for (int i = 0; i < 8; ++i) rowv[i] = *(const bf16x8*)&Vs[bi * 8 + i][bj * 8];
#pragma unroll
            for (int j = 0; j < 8; ++j) {
                bf16x8 t;
#pragma unroll
                for (int i = 0; i < 8; ++i) t[i] = rowv[i][j];
                *(bf16x8*)&Vt[bj * 8 + j][bi * 8] = t;
            }
        }

        // ---- S = Q K^T ----
        f32x4 sc[4] = {};
#pragma unroll
        for (int kk = 0; kk < 2; ++kk) {
#pragma unroll
            for (int n = 0; n < 4; ++n) {
                bf16x8 kf = *(const bf16x8*)&Ks[n * 16 + l15][kk * 32 + lg * 8];
                sc[n] = __builtin_amdgcn_mfma_f32_16x16x32_bf16(qf[kk], kf, sc[n], 0, 0, 0);
            }
        }

        // ---- mask + online softmax (C-layout: row=(lg)*4+j, col=l15+16n) ----
        const int qrow0 = qb + wave * 16 + lg * 4;
        const int key0 = k0 + l15;
        float mt[4];
#pragma unroll
        for (int j = 0; j < 4; ++j) mt[j] = m_run[j];
#pragma unroll
        for (int n = 0; n < 4; ++n) {
            int key = key0 + n * 16;
#pragma unroll
            for (int j = 0; j < 4; ++j) {
                float s = sc[n][j] * 0.125f;  // 1/sqrt(64)
                bool valid = (key <= qrow0 + j) && (key < len);
                s = valid ? s : -__builtin_inff();
                sc[n][j] = s;
                mt[j] = fmaxf(mt[j], s);
            }
        }
#pragma unroll
        for (int j = 0; j < 4; ++j) {
            float v = mt[j];
            v = fmaxf(v, __shfl_xor(v, 1));
            v = fmaxf(v, __shfl_xor(v, 2));
            v = fmaxf(v, __shfl_xor(v, 4));
            v = fmaxf(v, __shfl_xor(v, 8));
            mt[j] = v;
        }
        float pl[4] = {0.f, 0.f, 0.f, 0.f};
#pragma unroll
        for (int n = 0; n < 4; ++n) {
#pragma unroll
            for (int j = 0; j < 4; ++j) {
                float pv = __expf(sc[n][j] - mt[j]);
                pl[j] += pv;
                Ps[wave][lg * 4 + j][n * 16 + l15] = (__bf16)pv;
            }
        }
#pragma unroll
        for (int j = 0; j < 4; ++j) {
            float v = pl[j];
            v += __shfl_xor(v, 1);
            v += __shfl_xor(v, 2);
            v += __shfl_xor(v, 4);
            v += __shfl_xor(v, 8);
            float scale = __expf(m_run[j] - mt[j]);
            l_run[j] = l_run[j] * scale + v;
            m_run[j] = mt[j];
#pragma unroll
            for (int n = 0; n < 4; ++n) accO[n][j] *= scale;
        }
        __syncthreads();  // Vt ready for everyone; own-wave P ordered by lgkmcnt

        // ---- O += P V ----
#pragma unroll
        for (int kk = 0; kk < 2; ++kk) {
            bf16x8 pa = *(const bf16x8*)&Ps[wave][l15][kk * 32 + lg * 8];
#pragma unroll
            for (int n = 0; n < 4; ++n) {
                bf16x8 vb = *(const bf16x8*)&Vt[n * 16 + l15][kk * 32 + lg * 8];
                accO[n] = __builtin_amdgcn_mfma_f32_16x16x32_bf16(pa, vb, accO[n], 0, 0, 0);
            }
        }
        __syncthreads();  // protect Ks/Vs/Vt before next stage
    }

    // ---- epilogue: normalize, write bf16 [B*S][D] with heads re-interleaved ----
#pragma unroll
    for (int j = 0; j < 4; ++j) {
        float inv = 1.0f / l_run[j];
        int q = qb + wave * 16 + lg * 4 + j;
#pragma unroll
        for (int n = 0; n < 4; ++n) {
            Out[(size_t)(b * SEQ + q) * DMODEL + h * DHEAD + n * 16 + l15] =
                (__bf16)(accO[n][j] * inv);
        }
    }
}

extern "C" void kernel_launch(void* const* d_in, const int* in_sizes, int n_in,
                              void* d_out, int out_size, void* d_ws, size_t ws_size,
                              hipStream_t stream) {
    const float* query = (const float*)d_in[0];
    const unsigned char* mask = (const unsigned char*)d_in[1];
    const float* w_qkv = (const float*)d_in[2];
    const float* b_qkv = (const float*)d_in[3];
    const float* w_out = (const float*)d_in[4];
    const float* b_out = (const float*)d_in[5];
    float* out = (float*)d_out;

    // workspace carve (~34.5 MB)
    if (ws_size < 36176128ull) return;  // refuse to corrupt memory
    char* p = (char*)d_ws;
    int* lens = (int*)p;        p += 256;
    __bf16* Xb = (__bf16*)p;    p += (size_t)4096 * 768 * 2;
    __bf16* Wqb = (__bf16*)p;   p += (size_t)2304 * 768 * 2;
    __bf16* Wob = (__bf16*)p;   p += (size_t)768 * 768 * 2;
    __bf16* QKVb = (__bf16*)p;  p += (size_t)4096 * 2304 * 2;
    __bf16* AOb = (__bf16*)p;   p += (size_t)4096 * 768 * 2;

    lens_kernel<<<1, 256, 0, stream>>>(mask, lens);
    cvt_bf16_kernel<<<786432 / 256, 256, 0, stream>>>(query, Xb, 786432);
    cvt_bf16_kernel<<<442368 / 256, 256, 0, stream>>>(w_qkv, Wqb, 442368);
    cvt_bf16_kernel<<<147456 / 256, 256, 0, stream>>>(w_out, Wob, 147456);

    // QKV projection: [4096,768] @ [2304,768]^T -> bf16 [4096,2304]
    gemm_bt<0><<<dim3(32, 18), 256, 0, stream>>>(Xb, Wqb, b_qkv, QKVb, 4096, 2304, 768);
    // attention -> bf16 [4096,768]
    attn_kernel<<<dim3(32, 24), 256, 0, stream>>>(QKVb, lens, AOb);
    // output projection: [4096,768] @ [768,768]^T -> f32 d_out
    gemm_bt<1><<<dim3(32, 6), 256, 0, stream>>>(AOb, Wob, b_out, out, 4096, 768, 768);
}

// Round 3
// 162.505 us; speedup vs baseline: 1.2028x; 1.2028x over previous
//
#include <hip/hip_runtime.h>

#define BATCH 2
#define SEQ 2048
#define DMODEL 768
#define NH 12
#define DHEAD 64
#define D3 (3 * DMODEL)  // 2304

typedef float f32x4 __attribute__((ext_vector_type(4)));
typedef __bf16 bf16x8 __attribute__((ext_vector_type(8)));
typedef __bf16 bf16x4 __attribute__((ext_vector_type(4)));

__device__ __forceinline__ void g2l16(const void* g, void* l) {
    __builtin_amdgcn_global_load_lds(
        (const __attribute__((address_space(1))) void*)g,
        (__attribute__((address_space(3))) void*)l,
        16, 0, 0);
}

// ---------------- fused f32 -> bf16 convert for X, Wqkv, Wout ----------------
// counts are in float4 units (elements/4)
#define XQ 786432   // 2*2048*768 / 4
#define WQQ 442368  // 2304*768 / 4
#define WOQ 147456  // 768*768 / 4
__global__ __launch_bounds__(256) void cvt3_kernel(const float* __restrict__ X,
                                                   const float* __restrict__ Wq,
                                                   const float* __restrict__ Wo,
                                                   __bf16* __restrict__ Xb,
                                                   __bf16* __restrict__ Wqb,
                                                   __bf16* __restrict__ Wob) {
    int i = blockIdx.x * 256 + threadIdx.x;
    const float* s; __bf16* d; int k;
    if (i < XQ)            { s = X;  d = Xb;  k = i; }
    else if (i < XQ + WQQ) { s = Wq; d = Wqb; k = i - XQ; }
    else                   { s = Wo; d = Wob; k = i - XQ - WQQ; }
    float4 v = ((const float4*)s)[k];
    bf16x4 o;
    o[0] = (__bf16)v.x; o[1] = (__bf16)v.y; o[2] = (__bf16)v.z; o[3] = (__bf16)v.w;
    ((bf16x4*)d)[k] = o;
}

// ---------------- padding mask -> lengths, with dtype sniff ----------------
__global__ __launch_bounds__(256) void lens_kernel(const unsigned char* __restrict__ mask,
                                                   int* __restrict__ lens) {
    __shared__ int nz_s;
    __shared__ int cnt[2];
    if (threadIdx.x == 0) { nz_s = 0; cnt[0] = 0; cnt[1] = 0; }
    __syncthreads();
    uint4 mv = ((const uint4*)mask)[threadIdx.x];  // covers bytes [0,4096)
    if (mv.x | mv.y | mv.z | mv.w) nz_s = 1;
    __syncthreads();
    int c0 = 0, c1 = 0;
    if (nz_s) {  // bool layout, 1 byte/elem
        for (int s = threadIdx.x; s < SEQ; s += 256) {
            c0 += (mask[s] != 0);
            c1 += (mask[SEQ + s] != 0);
        }
    } else {     // int32 layout
        const int* mi = (const int*)mask;
        for (int s = threadIdx.x; s < SEQ; s += 256) {
            c0 += (mi[s] != 0);
            c1 += (mi[SEQ + s] != 0);
        }
    }
    atomicAdd(&cnt[0], c0);
    atomicAdd(&cnt[1], c1);
    __syncthreads();
    if (threadIdx.x == 0) { lens[0] = SEQ - cnt[0]; lens[1] = SEQ - cnt[1]; }
}

// ---------------- NT GEMM: C[M,N] = A[M,K] * Bw[N,K]^T + bias ----------------
// 128x128 tile, BK=64, 4 waves, global_load_lds staging, XOR-swizzled LDS.
template <int OUT_F32>
__global__ __launch_bounds__(256) void gemm_bt(const __bf16* __restrict__ A,
                                               const __bf16* __restrict__ Bw,
                                               const float* __restrict__ bias,
                                               void* __restrict__ Cout,
                                               int M, int N, int K) {
    __shared__ __align__(16) __bf16 As[128][64];
    __shared__ __align__(16) __bf16 Bs[128][64];
    const int tid = threadIdx.x;
    const int wave = tid >> 6, lane = tid & 63;
    const int bm = blockIdx.x * 128, bn = blockIdx.y * 128;
    const int wr = (wave >> 1) * 64, wc = (wave & 1) * 64;
    const int l15 = lane & 15, lg = lane >> 4;
    const int rsub = lane >> 3;                         // 0..7 (row within 8-row chunk)
    const int csub = (((lane & 7) ^ rsub) * 8);         // pre-swizzled source column
    const int rswz = (l15 & 7) * 8;                     // read-side XOR term

    f32x4 acc[4][4] = {};

    for (int kt = 0; kt < K; kt += 64) {
#pragma unroll
        for (int it = 0; it < 4; ++it) {
            int c = it * 4 + wave;      // chunk 0..15, 1KB each
            int row = c * 8 + rsub;
            g2l16(A + (size_t)(bm + row) * K + kt + csub, &As[0][0] + c * 512);
            g2l16(Bw + (size_t)(bn + row) * K + kt + csub, &Bs[0][0] + c * 512);
        }
        __syncthreads();
#pragma unroll
        for (int kk = 0; kk < 2; ++kk) {
            bf16x8 af[4], bfr[4];
            const int col = (kk * 32 + lg * 8) ^ rswz;
#pragma unroll
            for (int m = 0; m < 4; ++m)
                af[m] = *(const bf16x8*)(&As[0][0] + (wr + m * 16 + l15) * 64 + col);
#pragma unroll
            for (int n = 0; n < 4; ++n)
                bfr[n] = *(const bf16x8*)(&Bs[0][0] + (wc + n * 16 + l15) * 64 + col);
#pragma unroll
            for (int m = 0; m < 4; ++m)
#pragma unroll
                for (int n = 0; n < 4; ++n)
                    acc[m][n] = __builtin_amdgcn_mfma_f32_16x16x32_bf16(af[m], bfr[n], acc[m][n], 0, 0, 0);
        }
        __syncthreads();
    }

#pragma unroll
    for (int n = 0; n < 4; ++n) {
        int col = bn + wc + n * 16 + l15;
        float bv = bias[col];
#pragma unroll
        for (int m = 0; m < 4; ++m) {
#pragma unroll
            for (int j = 0; j < 4; ++j) {
                int row = bm + wr + m * 16 + lg * 4 + j;
                float v = acc[m][n][j] + bv;
                if (OUT_F32)
                    ((float*)Cout)[(size_t)row * N + col] = v;
                else
                    ((__bf16*)Cout)[(size_t)row * N + col] = (__bf16)v;
            }
        }
    }
}

// ---------------- flash attention: 1 block = 64 q-rows of one (b,h) ----------------
// log2-domain softmax; Ks XOR-swizzled; blockIdx scrambled for causal balance.
#define SCL 0.18033688011112042f  // (1/sqrt(64)) * log2(e)

__global__ __launch_bounds__(256) void attn_kernel(const __bf16* __restrict__ QKV,
                                                   const int* __restrict__ lens,
                                                   __bf16* __restrict__ Out) {
    __shared__ __align__(16) __bf16 Ks[64][64];     // K tile (XOR-swizzled layout)
    __shared__ __align__(16) __bf16 Vs[64][72];     // V tile staged [key][dh], padded
    __shared__ __align__(16) __bf16 Vt[64][72];     // V^T [dh][key], padded
    __shared__ __align__(16) __bf16 Ps[4][16][72];  // per-wave P [q][key], padded

    const int tid = threadIdx.x;
    const int wave = tid >> 6, lane = tid & 63;
    const int l15 = lane & 15, lg = lane >> 4;
    // scrambled work assignment: decorrelate work of blocks co-resident at stride 256
    const int id = blockIdx.x;
    const int bh = id % (BATCH * NH);
    const int jj = id / (BATCH * NH);
    const int qt = (jj * 7 + bh * 5) & 31;
    const int qb = qt * 64;
    const int b = bh / NH, h = bh % NH;
    const int len = lens[b];
    const __bf16* base = QKV + (size_t)b * SEQ * D3;
    const int rswz = (l15 & 7) * 8;

    // Q fragments (A-operand): row = lane&15, k = (lane>>4)*8 (+32 per kk)
    bf16x8 qf[2];
    {
        const __bf16* qp = base + (size_t)(qb + wave * 16 + l15) * D3 + h * DHEAD + lg * 8;
        qf[0] = *(const bf16x8*)qp;
        qf[1] = *(const bf16x8*)(qp + 32);
    }

    f32x4 accO[4] = {};
    float m_run[4], l_run[4];
#pragma unroll
    for (int j = 0; j < 4; ++j) { m_run[j] = -__builtin_inff(); l_run[j] = 0.f; }

    int kmax = qb + 64;
    if (len < kmax) kmax = len;
    const int ntiles = (kmax + 63) >> 6;

    for (int kt = 0; kt < ntiles; ++kt) {
        const int k0 = kt * 64;
        // ---- stage K (async direct-to-LDS, pre-swizzled source) ----
#pragma unroll
        for (int it = 0; it < 2; ++it) {
            int c = it * 4 + wave;
            int r = c * 8 + (lane >> 3);
            int srccol = ((lane & 7) ^ (lane >> 3)) * 8;
            g2l16(base + (size_t)(k0 + r) * D3 + DMODEL + h * DHEAD + srccol,
                  &Ks[0][0] + c * 512);
        }
        // ---- stage V (regs -> padded LDS) ----
#pragma unroll
        for (int it = 0; it < 2; ++it) {
            int idx = it * 256 + tid;
            int r = idx >> 3, c0 = (idx & 7) * 8;
            bf16x8 v = *(const bf16x8*)(base + (size_t)(k0 + r) * D3 + 2 * DMODEL + h * DHEAD + c0);
            *(bf16x8*)&Vs[r][c0] = v;
        }
        __syncthreads();

        // ---- transpose Vs -> Vt, one rotating wave, 8x8 blocks ----
        if (wave == (kt & 3)) {
            int bi = lane >> 3, bj = lane & 7;
            bf16x8 rowv[8];
#pragma unroll
            for (int i = 0; i < 8; ++i) rowv[i] = *(const bf16x8*)&Vs[bi * 8 + i][bj * 8];
#pragma unroll
            for (int j = 0; j < 8; ++j) {
                bf16x8 t;
#pragma unroll
                for (int i = 0; i < 8; ++i) t[i] = rowv[i][j];
                *(bf16x8*)&Vt[bj * 8 + j][bi * 8] = t;
            }
        }

        // ---- S = Q K^T (swizzled Ks reads) ----
        f32x4 sc[4] = {};
#pragma unroll
        for (int kk = 0; kk < 2; ++kk) {
            const int col = (kk * 32 + lg * 8) ^ rswz;
#pragma unroll
            for (int n = 0; n < 4; ++n) {
                bf16x8 kf = *(const bf16x8*)(&Ks[0][0] + (n * 16 + l15) * 64 + col);
                sc[n] = __builtin_amdgcn_mfma_f32_16x16x32_bf16(qf[kk], kf, sc[n], 0, 0, 0);
            }
        }

        // ---- mask + online softmax, log2 domain ----
        const int qrow0 = qb + wave * 16 + lg * 4;
        const int key0 = k0 + l15;
        float mt[4];
#pragma unroll
        for (int j = 0; j < 4; ++j) mt[j] = m_run[j];
#pragma unroll
        for (int n = 0; n < 4; ++n) {
            int key = key0 + n * 16;
#pragma unroll
            for (int j = 0; j < 4; ++j) {
                float s = sc[n][j] * SCL;
                bool valid = (key <= qrow0 + j) && (key < len);
                s = valid ? s : -__builtin_inff();
                sc[n][j] = s;
                mt[j] = fmaxf(mt[j], s);
            }
        }
#pragma unroll
        for (int j = 0; j < 4; ++j) {
            float v = mt[j];
            v = fmaxf(v, __shfl_xor(v, 1));
            v = fmaxf(v, __shfl_xor(v, 2));
            v = fmaxf(v, __shfl_xor(v, 4));
            v = fmaxf(v, __shfl_xor(v, 8));
            mt[j] = v;
        }
        float pl[4] = {0.f, 0.f, 0.f, 0.f};
#pragma unroll
        for (int n = 0; n < 4; ++n) {
#pragma unroll
            for (int j = 0; j < 4; ++j) {
                float pv = exp2f(sc[n][j] - mt[j]);
                pl[j] += pv;
                Ps[wave][lg * 4 + j][n * 16 + l15] = (__bf16)pv;
            }
        }
#pragma unroll
        for (int j = 0; j < 4; ++j) {
            float v = pl[j];
            v += __shfl_xor(v, 1);
            v += __shfl_xor(v, 2);
            v += __shfl_xor(v, 4);
            v += __shfl_xor(v, 8);
            float scale = exp2f(m_run[j] - mt[j]);
            l_run[j] = l_run[j] * scale + v;
            m_run[j] = mt[j];
#pragma unroll
            for (int n = 0; n < 4; ++n) accO[n][j] *= scale;
        }
        __syncthreads();  // Vt ready for everyone; own-wave P ordered by lgkmcnt

        // ---- O += P V ----
#pragma unroll
        for (int kk = 0; kk < 2; ++kk) {
            bf16x8 pa = *(const bf16x8*)&Ps[wave][l15][kk * 32 + lg * 8];
#pragma unroll
            for (int n = 0; n < 4; ++n) {
                bf16x8 vb = *(const bf16x8*)&Vt[n * 16 + l15][kk * 32 + lg * 8];
                accO[n] = __builtin_amdgcn_mfma_f32_16x16x32_bf16(pa, vb, accO[n], 0, 0, 0);
            }
        }
        __syncthreads();  // protect Ks/Vs/Vt before next stage
    }

    // ---- epilogue ----
#pragma unroll
    for (int j = 0; j < 4; ++j) {
        float inv = 1.0f / l_run[j];
        int q = qb + wave * 16 + lg * 4 + j;
#pragma unroll
        for (int n = 0; n < 4; ++n) {
            Out[(size_t)(b * SEQ + q) * DMODEL + h * DHEAD + n * 16 + l15] =
                (__bf16)(accO[n][j] * inv);
        }
    }
}

extern "C" void kernel_launch(void* const* d_in, const int* in_sizes, int n_in,
                              void* d_out, int out_size, void* d_ws, size_t ws_size,
                              hipStream_t stream) {
    const float* query = (const float*)d_in[0];
    const unsigned char* mask = (const unsigned char*)d_in[1];
    const float* w_qkv = (const float*)d_in[2];
    const float* b_qkv = (const float*)d_in[3];
    const float* w_out = (const float*)d_in[4];
    const float* b_out = (const float*)d_in[5];
    float* out = (float*)d_out;

    if (ws_size < 36176128ull) return;
    char* p = (char*)d_ws;
    int* lens = (int*)p;        p += 256;
    __bf16* Xb = (__bf16*)p;    p += (size_t)4096 * 768 * 2;
    __bf16* Wqb = (__bf16*)p;   p += (size_t)2304 * 768 * 2;
    __bf16* Wob = (__bf16*)p;   p += (size_t)768 * 768 * 2;
    __bf16* QKVb = (__bf16*)p;  p += (size_t)4096 * 2304 * 2;
    __bf16* AOb = (__bf16*)p;   p += (size_t)4096 * 768 * 2;

    lens_kernel<<<1, 256, 0, stream>>>(mask, lens);
    cvt3_kernel<<<(XQ + WQQ + WOQ) / 256, 256, 0, stream>>>(query, w_qkv, w_out, Xb, Wqb, Wob);

    // QKV projection: [4096,768] @ [2304,768]^T -> bf16 [4096,2304]
    gemm_bt<0><<<dim3(32, 18), 256, 0, stream>>>(Xb, Wqb, b_qkv, QKVb, 4096, 2304, 768);
    // attention -> bf16 [4096,768]
    attn_kernel<<<768, 256, 0, stream>>>(QKVb, lens, AOb);
    // output projection: [4096,768] @ [768,768]^T -> f32 d_out
    gemm_bt<1><<<dim3(32, 6), 256, 0, stream>>>(AOb, Wob, b_out, out, 4096, 768, 768);
}

// Round 5
// 162.318 us; speedup vs baseline: 1.2042x; 1.0011x over previous
//
#include <hip/hip_runtime.h>

#define BATCH 2
#define SEQ 2048
#define DMODEL 768
#define NH 12
#define DHEAD 64
#define D3 (3 * DMODEL)  // 2304
#define NITEMS 768       // 32 q-tiles * 24 (b,h)

typedef float f32x4 __attribute__((ext_vector_type(4)));
typedef __bf16 bf16x8 __attribute__((ext_vector_type(8)));
typedef __bf16 bf16x4 __attribute__((ext_vector_type(4)));

#define NEG_INF (-__builtin_inff())
#define SCL 0.18033688011112042f  // (1/sqrt(64)) * log2(e)

__device__ __forceinline__ void g2l16(const void* g, void* l) {
    __builtin_amdgcn_global_load_lds(
        (const __attribute__((address_space(1))) void*)g,
        (__attribute__((address_space(3))) void*)l,
        16, 0, 0);
}

__device__ __forceinline__ unsigned pack_bf16(float lo, float hi) {
    unsigned a = __builtin_bit_cast(unsigned short, (__bf16)lo);
    unsigned b = __builtin_bit_cast(unsigned short, (__bf16)hi);
    return a | (b << 16);
}

// ---------------- fused f32 -> bf16 convert (counts in float4 units) ----------------
#define XQ 786432   // 2*2048*768 / 4
#define WQQ 442368  // 2304*768 / 4
#define WOQ 147456  // 768*768 / 4
__global__ __launch_bounds__(256) void cvt3_kernel(const float* __restrict__ X,
                                                   const float* __restrict__ Wq,
                                                   const float* __restrict__ Wo,
                                                   __bf16* __restrict__ Xb,
                                                   __bf16* __restrict__ Wqb,
                                                   __bf16* __restrict__ Wob) {
    int i = blockIdx.x * 256 + threadIdx.x;
    const float* s; __bf16* d; int k;
    if (i < XQ)            { s = X;  d = Xb;  k = i; }
    else if (i < XQ + WQQ) { s = Wq; d = Wqb; k = i - XQ; }
    else                   { s = Wo; d = Wob; k = i - XQ - WQQ; }
    float4 v = ((const float4*)s)[k];
    bf16x4 o;
    o[0] = (__bf16)v.x; o[1] = (__bf16)v.y; o[2] = (__bf16)v.z; o[3] = (__bf16)v.w;
    ((bf16x4*)d)[k] = o;
}

// ---------------- padding mask -> lengths (+ zero the work counter) ----------------
__global__ __launch_bounds__(256) void lens_kernel(const unsigned char* __restrict__ mask,
                                                   int* __restrict__ lens) {
    __shared__ int nz_s;
    __shared__ int cnt[2];
    if (threadIdx.x == 0) { nz_s = 0; cnt[0] = 0; cnt[1] = 0; }
    __syncthreads();
    uint4 mv = ((const uint4*)mask)[threadIdx.x];  // covers bytes [0,4096)
    if (mv.x | mv.y | mv.z | mv.w) nz_s = 1;
    __syncthreads();
    int c0 = 0, c1 = 0;
    if (nz_s) {  // bool layout
        for (int s = threadIdx.x; s < SEQ; s += 256) {
            c0 += (mask[s] != 0);
            c1 += (mask[SEQ + s] != 0);
        }
    } else {     // int32 layout
        const int* mi = (const int*)mask;
        for (int s = threadIdx.x; s < SEQ; s += 256) {
            c0 += (mi[s] != 0);
            c1 += (mi[SEQ + s] != 0);
        }
    }
    atomicAdd(&cnt[0], c0);
    atomicAdd(&cnt[1], c1);
    __syncthreads();
    if (threadIdx.x == 0) {
        lens[0] = SEQ - cnt[0];
        lens[1] = SEQ - cnt[1];
        lens[2] = 0;  // work-queue counter for attn
    }
}

// ---------------- NT GEMM (unchanged, validated round 3) ----------------
template <int OUT_F32>
__global__ __launch_bounds__(256) void gemm_bt(const __bf16* __restrict__ A,
                                               const __bf16* __restrict__ Bw,
                                               const float* __restrict__ bias,
                                               void* __restrict__ Cout,
                                               int M, int N, int K) {
    __shared__ __align__(16) __bf16 As[128][64];
    __shared__ __align__(16) __bf16 Bs[128][64];
    const int tid = threadIdx.x;
    const int wave = tid >> 6, lane = tid & 63;
    const int bm = blockIdx.x * 128, bn = blockIdx.y * 128;
    const int wr = (wave >> 1) * 64, wc = (wave & 1) * 64;
    const int l15 = lane & 15, lg = lane >> 4;
    const int rsub = lane >> 3;
    const int csub = (((lane & 7) ^ rsub) * 8);
    const int rswz = (l15 & 7) * 8;

    f32x4 acc[4][4] = {};

    for (int kt = 0; kt < K; kt += 64) {
#pragma unroll
        for (int it = 0; it < 4; ++it) {
            int c = it * 4 + wave;
            int row = c * 8 + rsub;
            g2l16(A + (size_t)(bm + row) * K + kt + csub, &As[0][0] + c * 512);
            g2l16(Bw + (size_t)(bn + row) * K + kt + csub, &Bs[0][0] + c * 512);
        }
        __syncthreads();
#pragma unroll
        for (int kk = 0; kk < 2; ++kk) {
            bf16x8 af[4], bfr[4];
            const int col = (kk * 32 + lg * 8) ^ rswz;
#pragma unroll
            for (int m = 0; m < 4; ++m)
                af[m] = *(const bf16x8*)(&As[0][0] + (wr + m * 16 + l15) * 64 + col);
#pragma unroll
            for (int n = 0; n < 4; ++n)
                bfr[n] = *(const bf16x8*)(&Bs[0][0] + (wc + n * 16 + l15) * 64 + col);
#pragma unroll
            for (int m = 0; m < 4; ++m)
#pragma unroll
                for (int n = 0; n < 4; ++n)
                    acc[m][n] = __builtin_amdgcn_mfma_f32_16x16x32_bf16(af[m], bfr[n], acc[m][n], 0, 0, 0);
        }
        __syncthreads();
    }

#pragma unroll
    for (int n = 0; n < 4; ++n) {
        int col = bn + wc + n * 16 + l15;
        float bv = bias[col];
#pragma unroll
        for (int m = 0; m < 4; ++m) {
#pragma unroll
            for (int j = 0; j < 4; ++j) {
                int row = bm + wr + m * 16 + lg * 4 + j;
                float v = acc[m][n][j] + bv;
                if (OUT_F32)
                    ((float*)Cout)[(size_t)row * N + col] = v;
                else
                    ((__bf16*)Cout)[(size_t)row * N + col] = (__bf16)v;
            }
        }
    }
}

// ---------------- flash attention, swapped-QK^T, persistent blocks ----------------
// One item = 64 q-rows of one (b,h), popped from an atomic queue (lens[2]).
// Per wave: 16 q-rows (q = l15). S^T via mfma(K,Q); softmax in-lane + 2 shfl;
// P kept in registers, redistributed via shfl into the PV A-fragment;
// V double-buffered (g2l16, linear) and transposed in LDS by a rotating wave
// (round-3 verified path). 2 barriers/tile. T13 defer-rescale.
__global__ __launch_bounds__(256) void attn_kernel(const __bf16* __restrict__ QKV,
                                                   int* __restrict__ lens,
                                                   __bf16* __restrict__ Out) {
    __shared__ __align__(16) __bf16 Vs[2][4096];  // linear [key][64], 2 x 8KB
    __shared__ __align__(16) __bf16 Vt[64][72];   // V^T [dh][key], padded
    __shared__ int item_s;

    const int tid = threadIdx.x;
    const int wave = tid >> 6, lane = tid & 63;
    const int l15 = lane & 15, lg = lane >> 4;

    // V staging decode (linear): chunk c -> key row c>>3, dh col (c&7)*8
    int vk[2], vd[2];
#pragma unroll
    for (int j = 0; j < 2; ++j) {
        int c = (j * 4 + wave) * 64 + lane;
        vk[j] = c >> 3;
        vd[j] = (c & 7) * 8;
    }

    for (;;) {
        if (tid == 0) item_s = atomicAdd(&lens[2], 1);
        __syncthreads();
        const int item = item_s;
        if (item >= NITEMS) break;

        const int qt = 31 - (item / 24);  // LPT: heaviest first
        const int bh = item % 24;
        const int b = bh / NH, h = bh % NH;
        const int qb = qt * 64;
        const int len = lens[b];
        const __bf16* base = QKV + (size_t)b * SEQ * D3;
        const __bf16* kbase = base + DMODEL + h * DHEAD + (size_t)l15 * D3 + lg * 8;
        const __bf16* vsrc = base + 2 * DMODEL + h * DHEAD;

        // Q fragments (B-operand): col=q=l15, k = kk*32 + lg*8 + {0..7}
        bf16x8 qf0, qf1;
        {
            const __bf16* qp = base + (size_t)(qb + wave * 16 + l15) * D3 + h * DHEAD + lg * 8;
            qf0 = *(const bf16x8*)qp;
            qf1 = *(const bf16x8*)(qp + 32);
        }

        int kmax = qb + 64;
        if (len < kmax) kmax = len;
        const int ntiles = (kmax + 63) >> 6;
        const int myq = qb + wave * 16 + l15;
        const int qcap = (len - 1 < myq) ? (len - 1) : myq;  // valid: key <= qcap
        const int qmin = qb + wave * 16;

        f32x4 accO[4] = {};
        float m_run = NEG_INF, l_run = 0.f;

        // stage V tile 0 -> buf 0
#pragma unroll
        for (int j = 0; j < 2; ++j)
            g2l16(vsrc + (size_t)vk[j] * D3 + vd[j], &Vs[0][0] + (j * 4 + wave) * 512);
        __syncthreads();

        int cur = 0;
        for (int kt = 0; kt < ntiles; ++kt) {
            const int k0 = kt * 64;

            // stage next V tile (async; drained at the mid-iter barrier)
            if (kt + 1 < ntiles) {
#pragma unroll
                for (int j = 0; j < 2; ++j)
                    g2l16(vsrc + (size_t)(k0 + 64 + vk[j]) * D3 + vd[j],
                          &Vs[cur ^ 1][0] + (j * 4 + wave) * 512);
            }

            // K fragments (A-operand) direct from global/L2
            bf16x8 kf[2][4];
#pragma unroll
            for (int kk = 0; kk < 2; ++kk)
#pragma unroll
                for (int n = 0; n < 4; ++n)
                    kf[kk][n] = *(const bf16x8*)(kbase + (size_t)(k0 + n * 16) * D3 + kk * 32);

            // S^T = K Q^T : C row = key sub (lg*4+j), col = q (l15)
            f32x4 sc[4] = {};
            __builtin_amdgcn_s_setprio(1);
#pragma unroll
            for (int n = 0; n < 4; ++n) {
                sc[n] = __builtin_amdgcn_mfma_f32_16x16x32_bf16(kf[0][n], qf0, sc[n], 0, 0, 0);
                sc[n] = __builtin_amdgcn_mfma_f32_16x16x32_bf16(kf[1][n], qf1, sc[n], 0, 0, 0);
            }
            __builtin_amdgcn_s_setprio(0);

            // transpose Vs[cur] -> Vt, one rotating wave, 8x8 blocks (verified r3)
            if (wave == (kt & 3)) {
                int bi = lane >> 3, bj = lane & 7;
                bf16x8 rowv[8];
#pragma unroll
                for (int i = 0; i < 8; ++i)
                    rowv[i] = *(const bf16x8*)(&Vs[cur][0] + (bi * 8 + i) * 64 + bj * 8);
#pragma unroll
                for (int j2 = 0; j2 < 8; ++j2) {
                    bf16x8 t;
#pragma unroll
                    for (int i = 0; i < 8; ++i) t[i] = rowv[i][j2];
                    *(bf16x8*)&Vt[bj * 8 + j2][bi * 8] = t;
                }
            }

            // mask + scale (log2 domain)
            float v[4][4];
            const bool full = (k0 + 63 <= qmin) && (k0 + 63 < len);
            if (full) {
#pragma unroll
                for (int n = 0; n < 4; ++n)
#pragma unroll
                    for (int j = 0; j < 4; ++j) v[n][j] = sc[n][j] * SCL;
            } else {
#pragma unroll
                for (int n = 0; n < 4; ++n)
#pragma unroll
                    for (int j = 0; j < 4; ++j) {
                        int key = k0 + n * 16 + lg * 4 + j;
                        v[n][j] = (key <= qcap) ? sc[n][j] * SCL : NEG_INF;
                    }
            }

            // row max: in-lane tree + 2 cross-group shuffles
            float mn[4];
#pragma unroll
            for (int n = 0; n < 4; ++n)
                mn[n] = fmaxf(fmaxf(v[n][0], v[n][1]), fmaxf(v[n][2], v[n][3]));
            float mx = fmaxf(fmaxf(mn[0], mn[1]), fmaxf(mn[2], mn[3]));
            mx = fmaxf(mx, __shfl_xor(mx, 16));
            mx = fmaxf(mx, __shfl_xor(mx, 32));

            // T13 defer-rescale: keep old max when growth small (wave-uniform)
            const bool defer = __all(mx - m_run <= 8.0f);
            const float mnew = defer ? m_run : fmaxf(m_run, mx);

            // p = exp2(v - mnew), row sum, bf16 pack
            float psum = 0.f;
            unsigned pk[4][2];
#pragma unroll
            for (int n = 0; n < 4; ++n) {
                float p0 = exp2f(v[n][0] - mnew);
                float p1 = exp2f(v[n][1] - mnew);
                float p2 = exp2f(v[n][2] - mnew);
                float p3 = exp2f(v[n][3] - mnew);
                psum += (p0 + p1) + (p2 + p3);
                pk[n][0] = pack_bf16(p0, p1);
                pk[n][1] = pack_bf16(p2, p3);
            }
            psum += __shfl_xor(psum, 16);
            psum += __shfl_xor(psum, 32);

            if (defer) {
                l_run += psum;
            } else {
                const float scale = exp2f(m_run - mnew);
                l_run = l_run * scale + psum;
                m_run = mnew;
                float sc_j[4];
#pragma unroll
                for (int j = 0; j < 4; ++j) sc_j[j] = __shfl(scale, lg * 4 + j);
#pragma unroll
                for (int n = 0; n < 4; ++n)
#pragma unroll
                    for (int j = 0; j < 4; ++j) accO[n][j] *= sc_j[j];
            }

            // build PV A-fragments: lane needs P[q=l15][kk*32 + lg*8 + {0..7}]
            const int s0 = (lg & 1) * 32 + l15;
            bf16x8 pa[2];
#pragma unroll
            for (int kk = 0; kk < 2; ++kk) {
                unsigned d[4];
#pragma unroll
                for (int h2 = 0; h2 < 2; ++h2)
#pragma unroll
                    for (int r = 0; r < 2; ++r) {
                        unsigned u0 = (unsigned)__shfl((int)pk[kk * 2][r], s0 + h2 * 16);
                        unsigned u1 = (unsigned)__shfl((int)pk[kk * 2 + 1][r], s0 + h2 * 16);
                        d[h2 * 2 + r] = (lg & 2) ? u1 : u0;
                    }
                uint4 u = {d[0], d[1], d[2], d[3]};
                pa[kk] = __builtin_bit_cast(bf16x8, u);
            }

            __syncthreads();  // Vt written; next V tile landed (vmcnt drained)

            // O += P V  (B-operand from Vt[dh][key])
            __builtin_amdgcn_s_setprio(1);
#pragma unroll
            for (int kk = 0; kk < 2; ++kk)
#pragma unroll
                for (int n = 0; n < 4; ++n) {
                    bf16x8 vb = *(const bf16x8*)&Vt[n * 16 + l15][kk * 32 + lg * 8];
                    accO[n] = __builtin_amdgcn_mfma_f32_16x16x32_bf16(pa[kk], vb, accO[n], 0, 0, 0);
                }
            __builtin_amdgcn_s_setprio(0);

            __syncthreads();  // everyone done with Vt & Vs[cur]
            cur ^= 1;
        }

        // epilogue: O rows are q = lg*4+j; 1/l lives at lane with l15 = that q
        float inv = 1.0f / l_run;
        float inv_j[4];
#pragma unroll
        for (int j = 0; j < 4; ++j) inv_j[j] = __shfl(inv, lg * 4 + j);
#pragma unroll
        for (int n = 0; n < 4; ++n)
#pragma unroll
            for (int j = 0; j < 4; ++j) {
                int q = qb + wave * 16 + lg * 4 + j;
                Out[(size_t)(b * SEQ + q) * DMODEL + h * DHEAD + n * 16 + l15] =
                    (__bf16)(accO[n][j] * inv_j[j]);
            }
    }
}

extern "C" void kernel_launch(void* const* d_in, const int* in_sizes, int n_in,
                              void* d_out, int out_size, void* d_ws, size_t ws_size,
                              hipStream_t stream) {
    const float* query = (const float*)d_in[0];
    const unsigned char* mask = (const unsigned char*)d_in[1];
    const float* w_qkv = (const float*)d_in[2];
    const float* b_qkv = (const float*)d_in[3];
    const float* w_out = (const float*)d_in[4];
    const float* b_out = (const float*)d_in[5];
    float* out = (float*)d_out;

    if (ws_size < 36176128ull) return;
    char* p = (char*)d_ws;
    int* lens = (int*)p;        p += 256;
    __bf16* Xb = (__bf16*)p;    p += (size_t)4096 * 768 * 2;
    __bf16* Wqb = (__bf16*)p;   p += (size_t)2304 * 768 * 2;
    __bf16* Wob = (__bf16*)p;   p += (size_t)768 * 768 * 2;
    __bf16* QKVb = (__bf16*)p;  p += (size_t)4096 * 2304 * 2;
    __bf16* AOb = (__bf16*)p;   p += (size_t)4096 * 768 * 2;

    lens_kernel<<<1, 256, 0, stream>>>(mask, lens);
    cvt3_kernel<<<(XQ + WQQ + WOQ) / 256, 256, 0, stream>>>(query, w_qkv, w_out, Xb, Wqb, Wob);

    // QKV projection: [4096,768] @ [2304,768]^T -> bf16 [4096,2304]
    gemm_bt<0><<<dim3(32, 18), 256, 0, stream>>>(Xb, Wqb, b_qkv, QKVb, 4096, 2304, 768);
    // attention -> bf16 [4096,768]
    attn_kernel<<<1024, 256, 0, stream>>>(QKVb, lens, AOb);
    // output projection: [4096,768] @ [768,768]^T -> f32 d_out
    gemm_bt<1><<<dim3(32, 6), 256, 0, stream>>>(AOb, Wob, b_out, out, 4096, 768, 768);
}